// Round 1
// baseline (190.351 us; speedup 1.0000x reference)
//
#include <hip/hip_runtime.h>
#include <math.h>

#define ETA 1e-5f
#define MIN_SIGMA 1e-6f

constexpr int NB = 32;    // batch
constexpr int NN = 1024;  // N0 == N1
constexpr int ND = 128;   // D

// ws layout (in floats)
constexpr size_t OFF_MAXKEY = 0;                       // u32[32]
constexpr size_t OFF_DEN    = 32;                      // f32[32]
constexpr size_t OFF_RW     = 64;                      // f32[32*1024]
constexpr size_t OFF_CW     = OFF_RW + 32 * 1024;      // f32[32*1024]
constexpr size_t OFF_X0N    = OFF_CW + 32 * 1024;      // f32[1024]
constexpr size_t OFF_X1N    = OFF_X0N + 1024;          // f32[1024]
constexpr size_t OFF_AP     = OFF_X1N + 1024;          // f32[32*1024]
constexpr size_t OFF_BP     = OFF_AP + 32 * 1024;      // f32[32*1024]
constexpr size_t OFF_C2     = OFF_BP + 32 * 1024;      // f32[32]
constexpr size_t OFF_DOT    = ((OFF_C2 + 32 + 63) / 64) * 64;  // f32[1024*1024]

__device__ __forceinline__ unsigned fkey(float x) {
  unsigned u = __float_as_uint(x);
  return (u & 0x80000000u) ? ~u : (u | 0x80000000u);
}

// ---------------- norms: x0n[i], x1n[j] ----------------
__global__ __launch_bounds__(256) void k_norms(const float* __restrict__ x0,
                                               const float* __restrict__ x1,
                                               float* __restrict__ ws) {
  int tid = blockIdx.x * 256 + threadIdx.x;  // 0..2047
  bool is0 = tid < NN;
  int r = is0 ? tid : tid - NN;
  const float4* p = (const float4*)((is0 ? x0 : x1) + (size_t)r * ND);
  float s = 0.f;
#pragma unroll
  for (int k = 0; k < ND / 4; k++) {
    float4 v = p[k];
    s += v.x * v.x + v.y * v.y + v.z * v.z + v.w * v.w;
  }
  ws[(is0 ? OFF_X0N : OFF_X1N) + r] = s;
}

// ---------------- Ap[b,i], Bp[b,j], c2p[b] ----------------
// grid 128 blocks: block = (b<<2)|quarter ; thread -> one row i of x0 and x1
__global__ __launch_bounds__(256) void k_ab(const float* __restrict__ xt,
                                            const float* __restrict__ tarr,
                                            const float* __restrict__ x0,
                                            const float* __restrict__ x1,
                                            float* __restrict__ ws) {
  __shared__ __align__(16) float xts[ND];
  int b = blockIdx.x >> 2, q = blockIdx.x & 3;
  int tid = threadIdx.x;
  if (tid < ND) xts[tid] = xt[(size_t)b * ND + tid];
  __syncthreads();

  float tb = tarr[b];
  float omt = 1.f - tb;
  float ib2 = 1.f / ((tb + ETA) * (1.f - tb + ETA));

  float xtn = 0.f;
#pragma unroll
  for (int k4 = 0; k4 < ND / 4; k4++) {
    float4 xv = *(const float4*)&xts[k4 * 4];
    xtn += xv.x * xv.x + xv.y * xv.y + xv.z * xv.z + xv.w * xv.w;
  }

  int i = q * 256 + tid;
  float acc0 = 0.f, acc1 = 0.f;
#pragma unroll 8
  for (int k4 = 0; k4 < ND / 4; k4++) {
    float4 xv = *(const float4*)&xts[k4 * 4];
    float4 a = *(const float4*)(x0 + (size_t)i * ND + k4 * 4);
    float4 c = *(const float4*)(x1 + (size_t)i * ND + k4 * 4);
    acc0 += xv.x * a.x + xv.y * a.y + xv.z * a.z + xv.w * a.w;
    acc1 += xv.x * c.x + xv.y * c.y + xv.z * c.z + xv.w * c.w;
  }
  float x0n = ws[OFF_X0N + i], x1n = ws[OFF_X1N + i];
  ws[OFF_AP + (size_t)b * NN + i] =
      fmaf(omt * omt, x0n, fmaf(-2.f * omt, acc0, xtn)) * ib2;
  ws[OFF_BP + (size_t)b * NN + i] =
      fmaf(tb * tb, x1n, -2.f * tb * acc1) * ib2;
  if (q == 0 && tid == 0) ws[OFF_C2 + b] = 2.f * tb * omt * ib2;
}

// ---------------- dot tile GEMM + per-b max ----------------
__global__ __launch_bounds__(256) void k_dotmax(const float* __restrict__ x0,
                                                const float* __restrict__ x1,
                                                const float* __restrict__ sigw,
                                                float* __restrict__ ws) {
  __shared__ __align__(16) float As[32][36];
  __shared__ __align__(16) float Bs[32][36];
  __shared__ __align__(16) float ApS[32][34];
  __shared__ __align__(16) float BpS[32][34];
  __shared__ float x0nS[32], x1nS[32], c2S[32];
  __shared__ unsigned mkeyS[32];

  int tid = threadIdx.x;
  int tx = tid & 15, ty = tid >> 4;
  int i0 = blockIdx.y * 32, j0 = blockIdx.x * 32;

  {
    const float* Ap = ws + OFF_AP;
    const float* Bp = ws + OFF_BP;
#pragma unroll
    for (int rep = 0; rep < 4; rep++) {
      int idx = rep * 256 + tid;
      int b = idx >> 5, i = idx & 31;
      ApS[b][i] = Ap[(size_t)b * NN + i0 + i];
      BpS[b][i] = Bp[(size_t)b * NN + j0 + i];
    }
    if (tid < 32) {
      x0nS[tid] = ws[OFF_X0N + i0 + tid];
      x1nS[tid] = ws[OFF_X1N + j0 + tid];
      c2S[tid] = ws[OFF_C2 + tid];
      mkeyS[tid] = 0u;
    }
  }

  float c00 = 0.f, c01 = 0.f, c10 = 0.f, c11 = 0.f;
  int srow = tid >> 3, sk4 = tid & 7;
  for (int kc = 0; kc < 4; kc++) {
    __syncthreads();
    float4 a = *(const float4*)(x0 + (size_t)(i0 + srow) * ND + kc * 32 + sk4 * 4);
    float4 bb = *(const float4*)(x1 + (size_t)(j0 + srow) * ND + kc * 32 + sk4 * 4);
    As[sk4 * 4 + 0][srow] = a.x;
    As[sk4 * 4 + 1][srow] = a.y;
    As[sk4 * 4 + 2][srow] = a.z;
    As[sk4 * 4 + 3][srow] = a.w;
    Bs[sk4 * 4 + 0][srow] = bb.x;
    Bs[sk4 * 4 + 1][srow] = bb.y;
    Bs[sk4 * 4 + 2][srow] = bb.z;
    Bs[sk4 * 4 + 3][srow] = bb.w;
    __syncthreads();
#pragma unroll
    for (int k = 0; k < 32; k++) {
      float2 av = *(const float2*)&As[k][ty * 2];
      float2 bv = *(const float2*)&Bs[k][tx * 2];
      c00 = fmaf(av.x, bv.x, c00);
      c01 = fmaf(av.x, bv.y, c01);
      c10 = fmaf(av.y, bv.x, c10);
      c11 = fmaf(av.y, bv.y, c11);
    }
  }

  float* dot = ws + OFF_DOT;
  *(float2*)&dot[(size_t)(i0 + ty * 2 + 0) * NN + j0 + tx * 2] = make_float2(c00, c01);
  *(float2*)&dot[(size_t)(i0 + ty * 2 + 1) * NN + j0 + tx * 2] = make_float2(c10, c11);

  float swv = sigw[0];
  float sp = (swv > 20.f) ? swv : log1pf(__expf(swv));

  float dotv[2][2] = {{c00, c01}, {c10, c11}};
  float ninv[2][2], negL[2][2];
#pragma unroll
  for (int r = 0; r < 2; r++) {
    float xn0 = x0nS[ty * 2 + r];
#pragma unroll
    for (int c = 0; c < 2; c++) {
      float xn1 = x1nS[tx * 2 + c];
      float d01 = xn0 + xn1 - 2.f * dotv[r][c];
      float ss = fmaf(sp, sqrtf(fmaxf(d01, 0.f) * (1.f / 128.f)), MIN_SIGMA);
      ninv[r][c] = -0.5f / (ss * ss);
      negL[r][c] = -128.f * logf(ss);
    }
  }

  for (int b = 0; b < 32; b++) {
    float2 ap = *(const float2*)&ApS[b][ty * 2];
    float2 bp = *(const float2*)&BpS[b][tx * 2];
    float c2b = c2S[b];
    float m = -3.4e38f;
#pragma unroll
    for (int r = 0; r < 2; r++) {
      float apv = r ? ap.y : ap.x;
#pragma unroll
      for (int c = 0; c < 2; c++) {
        float bpv = c ? bp.y : bp.x;
        float t1 = apv + bpv;
        t1 = fmaf(c2b, dotv[r][c], t1);
        float core = fmaf(t1, ninv[r][c], negL[r][c]);
        m = fmaxf(m, core);
      }
    }
#pragma unroll
    for (int off = 1; off < 64; off <<= 1) m = fmaxf(m, __shfl_xor(m, off, 64));
    if ((tid & 63) == 0) atomicMax(&mkeyS[b], fkey(m));
  }
  __syncthreads();
  if (tid < 32) atomicMax(((unsigned*)ws) + OFF_MAXKEY + tid, mkeyS[tid]);
}

// ---------------- exp + row/col/den accumulation ----------------
__global__ __launch_bounds__(256) void k_expsum(const float* __restrict__ sigw,
                                                float* __restrict__ ws) {
  __shared__ __align__(16) float ApS[32][34];
  __shared__ __align__(16) float BpS[32][34];
  __shared__ float rowacc[32][32];
  __shared__ float colacc[32][32];
  __shared__ float denS[32], mS[32], x0nS[32], x1nS[32], c2S[32];

  int tid = threadIdx.x;
  int tx = tid & 15, ty = tid >> 4;
  int i0 = blockIdx.y * 32, j0 = blockIdx.x * 32;

  for (int idx = tid; idx < 32 * 32; idx += 256) ((float*)colacc)[idx] = 0.f;
  if (tid < 32) denS[tid] = 0.f;

  {
    const float* Ap = ws + OFF_AP;
    const float* Bp = ws + OFF_BP;
#pragma unroll
    for (int rep = 0; rep < 4; rep++) {
      int idx = rep * 256 + tid;
      int b = idx >> 5, i = idx & 31;
      ApS[b][i] = Ap[(size_t)b * NN + i0 + i];
      BpS[b][i] = Bp[(size_t)b * NN + j0 + i];
    }
    if (tid < 32) {
      x0nS[tid] = ws[OFF_X0N + i0 + tid];
      x1nS[tid] = ws[OFF_X1N + j0 + tid];
      c2S[tid] = ws[OFF_C2 + tid];
      unsigned u = ((const unsigned*)ws)[OFF_MAXKEY + tid];
      mS[tid] = (u & 0x80000000u) ? __uint_as_float(u & 0x7fffffffu)
                                  : __uint_as_float(~u);
    }
  }

  const float* dot = ws + OFF_DOT;
  float2 dv0 = *(const float2*)&dot[(size_t)(i0 + ty * 2 + 0) * NN + j0 + tx * 2];
  float2 dv1 = *(const float2*)&dot[(size_t)(i0 + ty * 2 + 1) * NN + j0 + tx * 2];
  float dotv[2][2] = {{dv0.x, dv0.y}, {dv1.x, dv1.y}};

  float swv = sigw[0];
  float sp = (swv > 20.f) ? swv : log1pf(__expf(swv));

  __syncthreads();

  float ninv[2][2], negL[2][2];
#pragma unroll
  for (int r = 0; r < 2; r++) {
    float xn0 = x0nS[ty * 2 + r];
#pragma unroll
    for (int c = 0; c < 2; c++) {
      float xn1 = x1nS[tx * 2 + c];
      float d01 = xn0 + xn1 - 2.f * dotv[r][c];
      float ss = fmaf(sp, sqrtf(fmaxf(d01, 0.f) * (1.f / 128.f)), MIN_SIGMA);
      ninv[r][c] = -0.5f / (ss * ss);
      negL[r][c] = -128.f * logf(ss);
    }
  }

  for (int b = 0; b < 32; b++) {
    float2 ap = *(const float2*)&ApS[b][ty * 2];
    float2 bp = *(const float2*)&BpS[b][tx * 2];
    float c2b = c2S[b];
    float mb = mS[b];
    float w[2][2];
#pragma unroll
    for (int r = 0; r < 2; r++) {
      float apv = r ? ap.y : ap.x;
#pragma unroll
      for (int c = 0; c < 2; c++) {
        float bpv = c ? bp.y : bp.x;
        float t1 = apv + bpv;
        t1 = fmaf(c2b, dotv[r][c], t1);
        float core = fmaf(t1, ninv[r][c], negL[r][c]);
        w[r][c] = __expf(core - mb);
      }
    }
    // rows: reduce over tx (bits 0..3)
    float r0 = w[0][0] + w[0][1], r1 = w[1][0] + w[1][1];
#pragma unroll
    for (int off = 1; off <= 8; off <<= 1) {
      r0 += __shfl_xor(r0, off, 64);
      r1 += __shfl_xor(r1, off, 64);
    }
    if (tx == 0) {
      rowacc[b][ty * 2 + 0] = r0;
      rowacc[b][ty * 2 + 1] = r1;
    }
    // cols: reduce over ty-in-wave (bits 4..5), then LDS atomic across waves
    float cc0 = w[0][0] + w[1][0], cc1 = w[0][1] + w[1][1];
    cc0 += __shfl_xor(cc0, 16, 64);
    cc1 += __shfl_xor(cc1, 16, 64);
    cc0 += __shfl_xor(cc0, 32, 64);
    cc1 += __shfl_xor(cc1, 32, 64);
    if (((tid >> 4) & 3) == 0) {
      atomicAdd(&colacc[b][tx * 2 + 0], cc0);
      atomicAdd(&colacc[b][tx * 2 + 1], cc1);
    }
    // den: wave total then LDS atomic
    float dvs = cc0 + cc1;
#pragma unroll
    for (int off = 1; off <= 8; off <<= 1) dvs += __shfl_xor(dvs, off, 64);
    if ((tid & 63) == 0) atomicAdd(&denS[b], dvs);
  }
  __syncthreads();

  float* rw = ws + OFF_RW;
  float* cw = ws + OFF_CW;
  float* den = ws + OFF_DEN;
  for (int idx = tid; idx < 1024; idx += 256) {
    int b = idx >> 5, i = idx & 31;
    atomicAdd(&rw[(size_t)b * NN + i0 + i], rowacc[b][i]);
    atomicAdd(&cw[(size_t)b * NN + j0 + i], colacc[b][i]);
  }
  if (tid < 32) atomicAdd(&den[tid], denS[tid]);
}

// ---------------- final combine ----------------
__global__ __launch_bounds__(256) void k_final(const float* __restrict__ xt,
                                               const float* __restrict__ tarr,
                                               const float* __restrict__ x0,
                                               const float* __restrict__ x1,
                                               const float* __restrict__ ws,
                                               float* __restrict__ out) {
  int b = blockIdx.x;
  int d = threadIdx.x & 127;
  int h = threadIdx.x >> 7;  // 0 or 1
  const float* rw = ws + OFF_RW + (size_t)b * NN;
  const float* cw = ws + OFF_CW + (size_t)b * NN;
  float a0 = 0.f, a1 = 0.f;
  int ibeg = h * 512, iend = ibeg + 512;
#pragma unroll 8
  for (int i = ibeg; i < iend; i++) {
    a0 = fmaf(rw[i], x0[(size_t)i * ND + d], a0);
    a1 = fmaf(cw[i], x1[(size_t)i * ND + d], a1);
  }
  __shared__ float s0[128], s1[128];
  if (h == 1) {
    s0[d] = a0;
    s1[d] = a1;
  }
  __syncthreads();
  if (h == 0) {
    a0 += s0[d];
    a1 += s1[d];
    float tb = tarr[b];
    float den = ws[OFF_DEN + b];
    float ct = (1.f - 2.f * tb) / (2.f * (tb + ETA) * (1.f - tb + ETA));
    float av = -1.f - ct * (1.f - tb);
    float bv = 1.f - ct * tb;
    float den_c = fmaxf(den, 1e-12f);
    out[(size_t)b * ND + d] = (ct * xt[(size_t)b * ND + d] * den + av * a0 + bv * a1) / den_c;
  }
}

extern "C" void kernel_launch(void* const* d_in, const int* in_sizes, int n_in,
                              void* d_out, int out_size, void* d_ws, size_t ws_size,
                              hipStream_t stream) {
  const float* xt = (const float*)d_in[0];
  const float* t = (const float*)d_in[1];
  const float* x0 = (const float*)d_in[2];
  const float* x1 = (const float*)d_in[3];
  const float* sw = (const float*)d_in[4];
  float* out = (float*)d_out;
  float* ws = (float*)d_ws;

  // zero accumulators: maxkey, den, rw, cw
  hipMemsetAsync(ws, 0, OFF_X0N * sizeof(float), stream);

  k_norms<<<8, 256, 0, stream>>>(x0, x1, ws);
  k_ab<<<128, 256, 0, stream>>>(xt, t, x0, x1, ws);
  k_dotmax<<<dim3(32, 32), 256, 0, stream>>>(x0, x1, sw, ws);
  k_expsum<<<dim3(32, 32), 256, 0, stream>>>(sw, ws);
  k_final<<<32, 256, 0, stream>>>(xt, t, x0, x1, ws, out);
}

// Round 3
// 168.613 us; speedup vs baseline: 1.1289x; 1.1289x over previous
//
#include <hip/hip_runtime.h>
#include <math.h>

#define ETA 1e-5f
#define MIN_SIGMA 1e-6f

constexpr int NN = 1024;  // N0 == N1
constexpr int ND = 128;   // D

// ws layout (in floats) -- zeroed region first [MAXKEY..CW)
constexpr size_t OFF_MAXKEY = 0;                       // u32[32]
constexpr size_t OFF_DEN    = 32;                      // f32[32]
constexpr size_t OFF_RW     = 64;                      // f32[32*1024]
constexpr size_t OFF_CW     = OFF_RW + 32 * 1024;      // f32[32*1024]
constexpr size_t OFF_X0N    = OFF_CW + 32 * 1024;      // f32[1024]
constexpr size_t OFF_X1N    = OFF_X0N + 1024;          // f32[1024]
constexpr size_t OFF_AP     = OFF_X1N + 1024;          // f32[32*1024]
constexpr size_t OFF_BP     = OFF_AP + 32 * 1024;      // f32[32*1024]
constexpr size_t OFF_C2     = OFF_BP + 32 * 1024;      // f32[32]
constexpr size_t OFF_DOT    = ((OFF_C2 + 32 + 63) / 64) * 64;  // f32[1024*1024]

__device__ __forceinline__ unsigned fkey(float x) {
  unsigned u = __float_as_uint(x);
  return (u & 0x80000000u) ? ~u : (u | 0x80000000u);
}
__device__ __forceinline__ float funkey(unsigned u) {
  return (u & 0x80000000u) ? __uint_as_float(u & 0x7fffffffu)
                           : __uint_as_float(~u);
}

// ---------------- Ap[b,i], Bp[b,j], c2[b], x0n, x1n ----------------
// grid 128 blocks: block = (b<<2)|quarter ; thread -> one row i
__global__ __launch_bounds__(256) void k_ab(const float* __restrict__ xt,
                                            const float* __restrict__ tarr,
                                            const float* __restrict__ x0,
                                            const float* __restrict__ x1,
                                            float* __restrict__ ws) {
  __shared__ __align__(16) float xts[ND];
  int b = blockIdx.x >> 2, q = blockIdx.x & 3;
  int tid = threadIdx.x;
  if (tid < ND) xts[tid] = xt[(size_t)b * ND + tid];
  __syncthreads();

  float tb = tarr[b];
  float omt = 1.f - tb;
  float ib2 = 1.f / ((tb + ETA) * (1.f - tb + ETA));

  float xtn = 0.f;
#pragma unroll
  for (int k4 = 0; k4 < ND / 4; k4++) {
    float4 xv = *(const float4*)&xts[k4 * 4];
    xtn += xv.x * xv.x + xv.y * xv.y + xv.z * xv.z + xv.w * xv.w;
  }

  int i = q * 256 + tid;
  float acc0 = 0.f, acc1 = 0.f, n0 = 0.f, n1 = 0.f;
#pragma unroll 8
  for (int k4 = 0; k4 < ND / 4; k4++) {
    float4 xv = *(const float4*)&xts[k4 * 4];
    float4 a = *(const float4*)(x0 + (size_t)i * ND + k4 * 4);
    float4 c = *(const float4*)(x1 + (size_t)i * ND + k4 * 4);
    acc0 += xv.x * a.x + xv.y * a.y + xv.z * a.z + xv.w * a.w;
    acc1 += xv.x * c.x + xv.y * c.y + xv.z * c.z + xv.w * c.w;
    n0 += a.x * a.x + a.y * a.y + a.z * a.z + a.w * a.w;
    n1 += c.x * c.x + c.y * c.y + c.z * c.z + c.w * c.w;
  }
  ws[OFF_AP + (size_t)b * NN + i] =
      fmaf(omt * omt, n0, fmaf(-2.f * omt, acc0, xtn)) * ib2;
  ws[OFF_BP + (size_t)b * NN + i] =
      fmaf(tb * tb, n1, -2.f * tb * acc1) * ib2;
  if (b == 0) {
    ws[OFF_X0N + i] = n0;
    ws[OFF_X1N + i] = n1;
  }
  if (q == 0 && tid == 0) ws[OFF_C2 + b] = 2.f * tb * omt * ib2;
}

// ---------------- k1: GEMM + QPR + per-b max (b-lane, no shuffles) ----
__global__ __launch_bounds__(256) void k1(const float* __restrict__ x0,
                                          const float* __restrict__ x1,
                                          const float* __restrict__ sigw,
                                          float* __restrict__ ws) {
  __shared__ __align__(16) float As[32][36];
  __shared__ __align__(16) float Bs[32][36];
  __shared__ __align__(16) float4 QPRS[32][32];
  __shared__ float ApT[32][33], BpT[32][33];
  __shared__ float x0nS[32], x1nS[32];
  __shared__ unsigned mS[32];

  int tid = threadIdx.x;
  int tx = tid & 15, ty = tid >> 4;
  int i0 = blockIdx.y * 32, j0 = blockIdx.x * 32;

  {
    const float* Ap = ws + OFF_AP;
    const float* Bp = ws + OFF_BP;
#pragma unroll
    for (int rep = 0; rep < 4; rep++) {
      int idx = rep * 256 + tid;
      int bb = idx >> 5, ii = idx & 31;
      ApT[ii][bb] = Ap[(size_t)bb * NN + i0 + ii];
      BpT[ii][bb] = Bp[(size_t)bb * NN + j0 + ii];
    }
    if (tid < 32) {
      x0nS[tid] = ws[OFF_X0N + i0 + tid];
      x1nS[tid] = ws[OFF_X1N + j0 + tid];
      mS[tid] = 0u;
    }
  }

  // GEMM 32x32x128 (2x2 per thread)
  float c00 = 0.f, c01 = 0.f, c10 = 0.f, c11 = 0.f;
  int srow = tid >> 3, sk4 = tid & 7;
  for (int kc = 0; kc < 4; kc++) {
    __syncthreads();
    float4 a = *(const float4*)(x0 + (size_t)(i0 + srow) * ND + kc * 32 + sk4 * 4);
    float4 bb = *(const float4*)(x1 + (size_t)(j0 + srow) * ND + kc * 32 + sk4 * 4);
    As[sk4 * 4 + 0][srow] = a.x;
    As[sk4 * 4 + 1][srow] = a.y;
    As[sk4 * 4 + 2][srow] = a.z;
    As[sk4 * 4 + 3][srow] = a.w;
    Bs[sk4 * 4 + 0][srow] = bb.x;
    Bs[sk4 * 4 + 1][srow] = bb.y;
    Bs[sk4 * 4 + 2][srow] = bb.z;
    Bs[sk4 * 4 + 3][srow] = bb.w;
    __syncthreads();
#pragma unroll
    for (int k = 0; k < 32; k++) {
      float2 av = *(const float2*)&As[k][ty * 2];
      float2 bv = *(const float2*)&Bs[k][tx * 2];
      c00 = fmaf(av.x, bv.x, c00);
      c01 = fmaf(av.x, bv.y, c01);
      c10 = fmaf(av.y, bv.x, c10);
      c11 = fmaf(av.y, bv.y, c11);
    }
  }

  // store dot for k2
  float* dot = ws + OFF_DOT;
  *(float2*)&dot[(size_t)(i0 + ty * 2 + 0) * NN + j0 + tx * 2] = make_float2(c00, c01);
  *(float2*)&dot[(size_t)(i0 + ty * 2 + 1) * NN + j0 + tx * 2] = make_float2(c10, c11);

  // QPR per point (log2 domain):
  // core2(b,i,j) = (Ap+Bp)*Q + c2*P + R,  Q=-log2e/(2 ss^2), P=dot*Q, R=-128*log2(ss)
  float swv = sigw[0];
  float sp = (swv > 20.f) ? swv : log1pf(__expf(swv));
  float dotv[2][2] = {{c00, c01}, {c10, c11}};
#pragma unroll
  for (int r = 0; r < 2; r++) {
#pragma unroll
    for (int c = 0; c < 2; c++) {
      float d01 = x0nS[ty * 2 + r] + x1nS[tx * 2 + c] - 2.f * dotv[r][c];
      float ss = fmaf(sp, sqrtf(fmaxf(d01, 0.f) * (1.f / 128.f)), MIN_SIGMA);
      float Q = -0.72134752044f / (ss * ss);
      float R = -128.f * __log2f(ss);
      QPRS[ty * 2 + r][tx * 2 + c] = make_float4(Q, dotv[r][c] * Q, R, 0.f);
    }
  }
  __syncthreads();

  // pass A: b-lane max (lane owns one b; rows rep*4..rep*4+3)
  int b = tid & 31, rep = tid >> 5;
  float c2b = ws[OFF_C2 + b];
  float bpreg[32];
#pragma unroll
  for (int j = 0; j < 32; j++) bpreg[j] = BpT[j][b];
  float m = -3.4e38f;
#pragma unroll
  for (int r = 0; r < 4; r++) {
    int i = rep * 4 + r;
    float ap = ApT[i][b];
#pragma unroll
    for (int j = 0; j < 32; j++) {
      float4 q4 = QPRS[i][j];
      float core = fmaf(ap + bpreg[j], q4.x, fmaf(c2b, q4.y, q4.z));
      m = fmaxf(m, core);
    }
  }
  atomicMax(&mS[b], fkey(m));
  __syncthreads();
  if (tid < 32) atomicMax((unsigned*)ws + OFF_MAXKEY + tid, mS[tid]);
}

// ---------------- k2: exp + row/col/den (b-lane, no shuffles) ---------
__global__ __launch_bounds__(256) void k2(const float* __restrict__ sigw,
                                          float* __restrict__ ws) {
  __shared__ __align__(16) float4 QPRS[32][32];
  __shared__ float ApT[32][33], BpT[32][33];
  __shared__ float colS[32][33], rowS[32][33];
  __shared__ float x0nS[32], x1nS[32];
  __shared__ float denS[32];

  int tid = threadIdx.x;
  int tx = tid & 15, ty = tid >> 4;
  int i0 = blockIdx.y * 32, j0 = blockIdx.x * 32;

  {
    const float* Ap = ws + OFF_AP;
    const float* Bp = ws + OFF_BP;
#pragma unroll
    for (int rep = 0; rep < 4; rep++) {
      int idx = rep * 256 + tid;
      int bb = idx >> 5, ii = idx & 31;
      ApT[ii][bb] = Ap[(size_t)bb * NN + i0 + ii];
      BpT[ii][bb] = Bp[(size_t)bb * NN + j0 + ii];
      colS[ii][bb] = 0.f;
    }
    if (tid < 32) {
      x0nS[tid] = ws[OFF_X0N + i0 + tid];
      x1nS[tid] = ws[OFF_X1N + j0 + tid];
      denS[tid] = 0.f;
    }
  }

  // load dot tile (global, no LDS dependency yet)
  const float* dot = ws + OFF_DOT;
  float2 dv0 = *(const float2*)&dot[(size_t)(i0 + ty * 2 + 0) * NN + j0 + tx * 2];
  float2 dv1 = *(const float2*)&dot[(size_t)(i0 + ty * 2 + 1) * NN + j0 + tx * 2];
  float dotv[2][2] = {{dv0.x, dv0.y}, {dv1.x, dv1.y}};
  float swv = sigw[0];
  float sp = (swv > 20.f) ? swv : log1pf(__expf(swv));

  // BARRIER: x0nS/x1nS written only by threads 0..31 above; all threads
  // read them in the QPR compute below. (This missing sync was round 2's NaN.)
  __syncthreads();

#pragma unroll
  for (int r = 0; r < 2; r++) {
#pragma unroll
    for (int c = 0; c < 2; c++) {
      float d01 = x0nS[ty * 2 + r] + x1nS[tx * 2 + c] - 2.f * dotv[r][c];
      float ss = fmaf(sp, sqrtf(fmaxf(d01, 0.f) * (1.f / 128.f)), MIN_SIGMA);
      float Q = -0.72134752044f / (ss * ss);
      float R = -128.f * __log2f(ss);
      QPRS[ty * 2 + r][tx * 2 + c] = make_float4(Q, dotv[r][c] * Q, R, 0.f);
    }
  }
  // BARRIER: QPRS fully written before pass B reads it.
  __syncthreads();

  // pass B: b-lane accumulation
  int b = tid & 31, rep = tid >> 5;
  float c2b = ws[OFF_C2 + b];
  float m2 = funkey(((const unsigned*)ws)[OFF_MAXKEY + b]);
  float bpreg[32];
#pragma unroll
  for (int j = 0; j < 32; j++) bpreg[j] = BpT[j][b];
  float colreg[32];
#pragma unroll
  for (int j = 0; j < 32; j++) colreg[j] = 0.f;
  float dreg = 0.f;
#pragma unroll
  for (int r = 0; r < 4; r++) {
    int i = rep * 4 + r;
    float ap = ApT[i][b];
    float rs = 0.f;
#pragma unroll
    for (int j = 0; j < 32; j++) {
      float4 q4 = QPRS[i][j];
      float core = fmaf(ap + bpreg[j], q4.x, fmaf(c2b, q4.y, q4.z));
      float w = exp2f(core - m2);
      rs += w;
      colreg[j] += w;
    }
    rowS[i][b] = rs;  // unique owner -> plain store
    dreg += rs;
  }
#pragma unroll
  for (int j = 0; j < 32; j++) atomicAdd(&colS[j][b], colreg[j]);
  atomicAdd(&denS[b], dreg);
  __syncthreads();

  // coalesced flush to global accumulators
  float* rw = ws + OFF_RW;
  float* cw = ws + OFF_CW;
#pragma unroll
  for (int k = 0; k < 4; k++) {
    int idx = k * 256 + tid;
    int bb = idx >> 5, ii = idx & 31;
    atomicAdd(&rw[(size_t)bb * NN + i0 + ii], rowS[ii][bb]);
    atomicAdd(&cw[(size_t)bb * NN + j0 + ii], colS[ii][bb]);
  }
  if (tid < 32) atomicAdd(ws + OFF_DEN + tid, denS[tid]);
}

// ---------------- k3: weighted combine + output ----------------
// grid 128 blocks: (b, d-quarter); x0/x1 read once total across grid
__global__ __launch_bounds__(256) void k3(const float* __restrict__ xt,
                                          const float* __restrict__ tarr,
                                          const float* __restrict__ x0,
                                          const float* __restrict__ x1,
                                          const float* __restrict__ ws,
                                          float* __restrict__ out) {
  int b = blockIdx.x >> 2, dq = blockIdx.x & 3;
  int tid = threadIdx.x;
  int d = dq * 32 + (tid & 31);
  int h = tid >> 5;  // 0..7, each handles 128 rows
  const float* rw = ws + OFF_RW + (size_t)b * NN;
  const float* cw = ws + OFF_CW + (size_t)b * NN;
  float a0 = 0.f, a1 = 0.f;
  int ibeg = h * 128;
#pragma unroll 4
  for (int k = 0; k < 128; k++) {
    int i = ibeg + k;
    a0 = fmaf(rw[i], x0[(size_t)i * ND + d], a0);
    a1 = fmaf(cw[i], x1[(size_t)i * ND + d], a1);
  }
  __shared__ float s0[8][32], s1[8][32];
  s0[h][tid & 31] = a0;
  s1[h][tid & 31] = a1;
  __syncthreads();
  if (tid < 32) {
    float A0 = 0.f, A1 = 0.f;
#pragma unroll
    for (int hh = 0; hh < 8; hh++) {
      A0 += s0[hh][tid];
      A1 += s1[hh][tid];
    }
    float tb = tarr[b];
    float den = ws[OFF_DEN + b];
    float ct = (1.f - 2.f * tb) / (2.f * (tb + ETA) * (1.f - tb + ETA));
    float av = -1.f - ct * (1.f - tb);
    float bv = 1.f - ct * tb;
    float den_c = fmaxf(den, 1e-12f);
    out[(size_t)b * ND + d] =
        (ct * xt[(size_t)b * ND + d] * den + av * A0 + bv * A1) / den_c;
  }
}

extern "C" void kernel_launch(void* const* d_in, const int* in_sizes, int n_in,
                              void* d_out, int out_size, void* d_ws, size_t ws_size,
                              hipStream_t stream) {
  const float* xt = (const float*)d_in[0];
  const float* t = (const float*)d_in[1];
  const float* x0 = (const float*)d_in[2];
  const float* x1 = (const float*)d_in[3];
  const float* sw = (const float*)d_in[4];
  float* out = (float*)d_out;
  float* ws = (float*)d_ws;

  // zero accumulators: maxkey, den, rw, cw
  hipMemsetAsync(ws, 0, OFF_X0N * sizeof(float), stream);

  k_ab<<<128, 256, 0, stream>>>(xt, t, x0, x1, ws);
  k1<<<dim3(32, 32), 256, 0, stream>>>(x0, x1, sw, ws);
  k2<<<dim3(32, 32), 256, 0, stream>>>(sw, ws);
  k3<<<128, 256, 0, stream>>>(xt, t, x0, x1, ws, out);
}